// Round 1
// baseline (235.250 us; speedup 1.0000x reference)
//
#include <hip/hip_runtime.h>

#define MDIM 512
#define NDIM 8192
#define KDIM 8192
#define BM 128
#define BN 128
#define BK 64
#define NKT (KDIM / BK)  // 128

typedef short v8s __attribute__((ext_vector_type(8)));
typedef float v4f __attribute__((ext_vector_type(4)));
typedef int   v4i __attribute__((ext_vector_type(4)));

#define GLDS16(g, l)                                                    \
  __builtin_amdgcn_global_load_lds(                                     \
      (const __attribute__((address_space(1))) void*)(g),               \
      (__attribute__((address_space(3))) void*)(l), 16, 0, 0)

// pack two f32 into two bf16 by truncation (high halves) via byte-perm
__device__ __forceinline__ unsigned pack_bf2(float a, float b) {
  unsigned ia = __builtin_bit_cast(unsigned, a);
  unsigned ib = __builtin_bit_cast(unsigned, b);
  return __builtin_amdgcn_perm(ib, ia, 0x07060302u);  // lo16=a.hi, hi16=b.hi
}

// same but round-to-nearest (+0x8000 before truncation); inputs are finite
__device__ __forceinline__ unsigned pack_bf2_rnd(float a, float b) {
  unsigned ia = __builtin_bit_cast(unsigned, a) + 0x8000u;
  unsigned ib = __builtin_bit_cast(unsigned, b) + 0x8000u;
  return __builtin_amdgcn_perm(ib, ia, 0x07060302u);
}

// x fp32 -> bf16 (as shorts) into workspace
__global__ __launch_bounds__(256) void cvt_x_kernel(const float* __restrict__ x,
                                                    short* __restrict__ xb) {
  const int i = (blockIdx.x * 256 + threadIdx.x) * 8;
  v4f f0 = *(const v4f*)(x + i);
  v4f f1 = *(const v4f*)(x + i + 4);
  v4i o;
  o[0] = pack_bf2_rnd(f0[0], f0[1]);
  o[1] = pack_bf2_rnd(f0[2], f0[3]);
  o[2] = pack_bf2_rnd(f1[0], f1[1]);
  o[3] = pack_bf2_rnd(f1[2], f1[3]);
  *(v4i*)(xb + i) = o;
}

// Fused dequant GEMM: out = x(bf16) * dequant(wq)^T
// XWS: A comes from pre-converted bf16 in ws (global_load_lds);
// else A staged from fp32 x with in-kernel conversion.
template <bool XWS>
__global__ __launch_bounds__(256, 1) void gemm_q_kernel(
    const short* __restrict__ xb, const float* __restrict__ xf,
    const int* __restrict__ wq, const float* __restrict__ wsc,
    float* __restrict__ out) {
  __shared__ short lA[2][BM * BK];
  __shared__ short lB[2][BN * BK];

  // XCD-aware bijective swizzle (256 blocks, 8 XCDs): XCD x gets n-tiles
  // 8x..8x+7 with all 4 m-tiles -> weight tile shared in that XCD's L2.
  const int b = blockIdx.x;
  const int swz = ((b & 7) << 5) | (b >> 3);
  const int mt = swz & 3;
  const int nt = swz >> 2;
  const int m0 = mt * BM;
  const int n0 = nt * BN;

  const int t = threadIdx.x;
  const int w = t >> 6;
  const int l = t & 63;
  const int wm = (w >> 1) * 64;  // wave tile origin within block tile
  const int wn = (w & 1) * 64;

  // staging mapping: unit8 = p*256 + t covers 8 consecutive elems;
  // row = p*32 + (t>>3), col = (t&7)*8
  const int urow = t >> 3;
  const int ucol = (t & 7) * 8;

  v4f acc[4][4] = {};
  v4i breg[4][2];
  v4f areg[4][2];

  auto issue_loads = [&](int k0, int buf) {
    const int* gB = wq + (size_t)n0 * KDIM + k0;
#pragma unroll
    for (int p = 0; p < 4; ++p) {
      const int* gp = gB + (size_t)(p * 32 + urow) * KDIM + ucol;
      breg[p][0] = *(const v4i*)gp;
      breg[p][1] = *(const v4i*)(gp + 4);
    }
    if constexpr (XWS) {
      const short* gA = xb + (size_t)m0 * KDIM + k0;
#pragma unroll
      for (int it = 0; it < 4; ++it) {
        const int u = (it * 4 + w) * 64 + l;  // 16-byte units
        const short* gp = gA + (size_t)(u >> 3) * KDIM + (u & 7) * 8;
        GLDS16(gp, &lA[buf][(it * 4 + w) * 512]);  // wave-uniform LDS base
      }
    } else {
      const float* gA = xf + (size_t)m0 * KDIM + k0;
#pragma unroll
      for (int p = 0; p < 4; ++p) {
        const float* gp = gA + (size_t)(p * 32 + urow) * KDIM + ucol;
        areg[p][0] = *(const v4f*)gp;
        areg[p][1] = *(const v4f*)(gp + 4);
      }
    }
  };

  auto write_stage = [&](int buf, float s) {
#pragma unroll
    for (int p = 0; p < 4; ++p) {
      v4i o;
      o[0] = pack_bf2(s * (float)breg[p][0][0], s * (float)breg[p][0][1]);
      o[1] = pack_bf2(s * (float)breg[p][0][2], s * (float)breg[p][0][3]);
      o[2] = pack_bf2(s * (float)breg[p][1][0], s * (float)breg[p][1][1]);
      o[3] = pack_bf2(s * (float)breg[p][1][2], s * (float)breg[p][1][3]);
      *(v4i*)&lB[buf][(p * 32 + urow) * BK + ucol] = o;
      if constexpr (!XWS) {
        v4i oa;
        oa[0] = pack_bf2(areg[p][0][0], areg[p][0][1]);
        oa[1] = pack_bf2(areg[p][0][2], areg[p][0][3]);
        oa[2] = pack_bf2(areg[p][1][0], areg[p][1][1]);
        oa[3] = pack_bf2(areg[p][1][2], areg[p][1][3]);
        *(v4i*)&lA[buf][(p * 32 + urow) * BK + ucol] = oa;
      }
    }
  };

  auto compute = [&](int buf) {
#pragma unroll
    for (int kk = 0; kk < 2; ++kk) {
      const int kof = kk * 32 + (l >> 4) * 8;
      v8s af[4], bfq[4];
#pragma unroll
      for (int i = 0; i < 4; ++i) {
        af[i] = *(const v8s*)&lA[buf][(wm + i * 16 + (l & 15)) * BK + kof];
        bfq[i] = *(const v8s*)&lB[buf][(wn + i * 16 + (l & 15)) * BK + kof];
      }
#pragma unroll
      for (int i = 0; i < 4; ++i)
#pragma unroll
        for (int j = 0; j < 4; ++j)
          acc[i][j] = __builtin_amdgcn_mfma_f32_16x16x32_bf16(
              af[i], bfq[j], acc[i][j], 0, 0, 0);
    }
  };

  // prologue: fully stage tile 0 into buf 0
  issue_loads(0, 0);
  write_stage(0, wsc[nt * 64]);

  for (int kt = 0; kt < NKT; ++kt) {
    const int cur = kt & 1;
    __syncthreads();  // buf[cur] ready (drains glds vmcnt + ds_write lgkm)
    if (kt + 1 < NKT) issue_loads((kt + 1) * BK, cur ^ 1);  // async, early
    compute(cur);                                           // hides latency
    if (kt + 1 < NKT) {
      const float s = wsc[nt * 64 + ((kt + 1) >> 1)];  // one scale / K-tile
      write_stage(cur ^ 1, s);                         // cvt + ds_write, late
    }
  }

  // epilogue: C/D mapping col=lane&15, row=(lane>>4)*4+reg
#pragma unroll
  for (int i = 0; i < 4; ++i) {
#pragma unroll
    for (int j = 0; j < 4; ++j) {
      const int mrow = m0 + wm + i * 16 + (l >> 4) * 4;
      const int ocol = n0 + wn + j * 16 + (l & 15);
#pragma unroll
      for (int r = 0; r < 4; ++r)
        out[(size_t)(mrow + r) * NDIM + ocol] = acc[i][j][r];
    }
  }
}

extern "C" void kernel_launch(void* const* d_in, const int* in_sizes, int n_in,
                              void* d_out, int out_size, void* d_ws,
                              size_t ws_size, hipStream_t stream) {
  const float* x = (const float*)d_in[0];
  const int* wq = (const int*)d_in[1];
  const float* wsc = (const float*)d_in[2];
  float* out = (float*)d_out;

  const size_t xb_bytes = (size_t)MDIM * KDIM * sizeof(short);
  if (ws_size >= xb_bytes) {
    short* xb = (short*)d_ws;
    cvt_x_kernel<<<dim3((MDIM * KDIM) / (256 * 8)), dim3(256), 0, stream>>>(x, xb);
    gemm_q_kernel<true><<<dim3(256), dim3(256), 0, stream>>>(xb, x, wq, wsc, out);
  } else {
    gemm_q_kernel<false><<<dim3(256), dim3(256), 0, stream>>>(nullptr, x, wq, wsc, out);
  }
}

// Round 2
// 178.821 us; speedup vs baseline: 1.3156x; 1.3156x over previous
//
#include <hip/hip_runtime.h>

#define MDIM 512
#define NDIM 8192
#define KDIM 8192
#define BM 128
#define BN 128
#define BK 64

typedef short v8s __attribute__((ext_vector_type(8)));
typedef float v4f __attribute__((ext_vector_type(4)));
typedef int   v4i __attribute__((ext_vector_type(4)));

#define GLDS16(g, l)                                                    \
  __builtin_amdgcn_global_load_lds(                                     \
      (const __attribute__((address_space(1))) void*)(g),               \
      (__attribute__((address_space(3))) void*)(l), 16, 0, 0)

// pack two f32 into two bf16 by truncation (high halves) via byte-perm
__device__ __forceinline__ unsigned pack_bf2(float a, float b) {
  unsigned ia = __builtin_bit_cast(unsigned, a);
  unsigned ib = __builtin_bit_cast(unsigned, b);
  return __builtin_amdgcn_perm(ib, ia, 0x07060302u);  // lo16=a.hi, hi16=b.hi
}

// round-to-nearest-ish (+0x8000 before truncation); inputs finite
__device__ __forceinline__ unsigned pack_bf2_rnd(float a, float b) {
  unsigned ia = __builtin_bit_cast(unsigned, a) + 0x8000u;
  unsigned ib = __builtin_bit_cast(unsigned, b) + 0x8000u;
  return __builtin_amdgcn_perm(ib, ia, 0x07060302u);
}

// x fp32 -> bf16, tiled [4 mtile][128 ktile][1024 units] with the k-unit
// XOR-swizzle PRE-APPLIED so the gemm's linear global_load_lds lands the
// swizzled layout in LDS (rule: glds dest is linear; permute the source).
// Unit u within a tile: row = u>>3, slot = u&7; slot holds k-units
// (slot ^ (row&7)).
__global__ __launch_bounds__(256) void cvt_x_kernel(const float* __restrict__ x,
                                                    short* __restrict__ xb) {
  const int g = blockIdx.x * 256 + threadIdx.x;       // global unit id
  const int mt = g >> 17;                             // /131072
  const int rem = g & 131071;
  const int kt = rem >> 10;
  const int u = rem & 1023;
  const int row = u >> 3;
  const int slot = u & 7;
  const int m = mt * BM + row;
  const int k = kt * BK + ((slot ^ (row & 7)) << 3);
  const float* src = x + (size_t)m * KDIM + k;
  v4f f0 = *(const v4f*)src;
  v4f f1 = *(const v4f*)(src + 4);
  v4i o;
  o[0] = pack_bf2_rnd(f0[0], f0[1]);
  o[1] = pack_bf2_rnd(f0[2], f0[3]);
  o[2] = pack_bf2_rnd(f1[0], f1[1]);
  o[3] = pack_bf2_rnd(f1[2], f1[3]);
  *(v4i*)(xb + (size_t)g * 8) = o;
}

// out[i] = p0[i] + p1[i]  (split-K reduction, deterministic)
__global__ __launch_bounds__(256) void reduce_kernel(const float* __restrict__ p,
                                                     float* __restrict__ out) {
  const size_t i = ((size_t)blockIdx.x * 256 + threadIdx.x) * 4;
  v4f a = *(const v4f*)(p + i);
  v4f b = *(const v4f*)(p + (size_t)MDIM * NDIM + i);
  *(v4f*)(out + i) = a + b;
}

// Fused dequant GEMM: out = x(bf16) * dequant(wq)^T
// SPLIT: 2-way split-K, grid 512, partials to outp[kh]
// AWS:   A from pre-swizzled bf16 ws via global_load_lds; else reg-staged fp32
template <bool SPLIT, bool AWS>
__global__ __launch_bounds__(256, 2) void gemm_q_kernel(
    const short* __restrict__ xb, const float* __restrict__ xf,
    const int* __restrict__ wq, const float* __restrict__ wsc,
    float* __restrict__ outp) {
  __shared__ short lA[2][BM * BK];
  __shared__ short lB[2][BN * BK];

  // XCD-aware swizzle: XCD x gets a contiguous chunk of the (nt,kh,mt) space
  // -> its 8 n-tiles' weight stream is shared in that XCD's L2.
  const int b = blockIdx.x;
  int mt, nt, kh;
  if constexpr (SPLIT) {
    const int s = ((b & 7) << 6) | (b >> 3);
    mt = s & 3; kh = (s >> 2) & 1; nt = s >> 3;
  } else {
    const int s = ((b & 7) << 5) | (b >> 3);
    mt = s & 3; kh = 0; nt = s >> 2;
  }
  const int m0 = mt * BM;
  const int n0 = nt * BN;
  const int nkt = SPLIT ? 64 : 128;
  const int kbase = SPLIT ? kh * 4096 : 0;
  const int sbase = nt * 64 + (SPLIT ? kh * 32 : 0);

  const int t = threadIdx.x;
  const int w = t >> 6;
  const int l = t & 63;
  const int wm = (w >> 1) * 64;
  const int wn = (w & 1) * 64;

  // staging: thread covers 8 consecutive k at (row = p*32 + urow, unit cu)
  const int urow = t >> 3;   // 0..31
  const int cu = t & 7;      // k-unit within row
  const int wslot = ((cu ^ (urow & 7)) << 3);  // swizzled elem offset in row

  v4f acc[4][4] = {};
  v4i breg[4][2];
  v4f areg[4][2];

  auto issue_loads = [&](int ktl, int buf) {
    const int* gB = wq + (size_t)n0 * KDIM + kbase + ktl * 64;
#pragma unroll
    for (int p = 0; p < 4; ++p) {
      const int* gp = gB + (size_t)(p * 32 + urow) * KDIM + cu * 8;
      breg[p][0] = *(const v4i*)gp;
      breg[p][1] = *(const v4i*)(gp + 4);
    }
    if constexpr (AWS) {
      const int ktg = (SPLIT ? kh * 64 : 0) + ktl;
      const short* gA = xb + ((size_t)mt * 131072 + (size_t)ktg * 1024) * 8;
#pragma unroll
      for (int it = 0; it < 4; ++it) {
        const int ub = (it * 4 + w) * 64;  // wave-uniform unit base
        GLDS16(gA + (size_t)(ub + l) * 8, &lA[buf][ub * 8]);
      }
    } else {
      const float* gA = xf + (size_t)m0 * KDIM + kbase + ktl * 64;
#pragma unroll
      for (int p = 0; p < 4; ++p) {
        const float* gp = gA + (size_t)(p * 32 + urow) * KDIM + cu * 8;
        areg[p][0] = *(const v4f*)gp;
        areg[p][1] = *(const v4f*)(gp + 4);
      }
    }
  };

  auto write_stage = [&](int buf, float s) {
#pragma unroll
    for (int p = 0; p < 4; ++p) {
      v4i o;
      o[0] = pack_bf2(s * (float)breg[p][0][0], s * (float)breg[p][0][1]);
      o[1] = pack_bf2(s * (float)breg[p][0][2], s * (float)breg[p][0][3]);
      o[2] = pack_bf2(s * (float)breg[p][1][0], s * (float)breg[p][1][1]);
      o[3] = pack_bf2(s * (float)breg[p][1][2], s * (float)breg[p][1][3]);
      *(v4i*)&lB[buf][(p * 32 + urow) * BK + wslot] = o;
      if constexpr (!AWS) {
        v4i oa;
        oa[0] = pack_bf2_rnd(areg[p][0][0], areg[p][0][1]);
        oa[1] = pack_bf2_rnd(areg[p][0][2], areg[p][0][3]);
        oa[2] = pack_bf2_rnd(areg[p][1][0], areg[p][1][1]);
        oa[3] = pack_bf2_rnd(areg[p][1][2], areg[p][1][3]);
        *(v4i*)&lA[buf][(p * 32 + urow) * BK + wslot] = oa;
      }
    }
  };

  auto compute = [&](int buf) {
#pragma unroll
    for (int kk = 0; kk < 2; ++kk) {
      const int q = kk * 4 + (l >> 4);  // k-unit index 0..7
      v8s af[4], bq[4];
#pragma unroll
      for (int i = 0; i < 4; ++i) {
        const int ra = wm + i * 16 + (l & 15);
        af[i] = *(const v8s*)&lA[buf][ra * BK + ((q ^ (ra & 7)) << 3)];
        const int rb = wn + i * 16 + (l & 15);
        bq[i] = *(const v8s*)&lB[buf][rb * BK + ((q ^ (rb & 7)) << 3)];
      }
#pragma unroll
      for (int i = 0; i < 4; ++i)
#pragma unroll
        for (int j = 0; j < 4; ++j)
          acc[i][j] = __builtin_amdgcn_mfma_f32_16x16x32_bf16(
              af[i], bq[j], acc[i][j], 0, 0, 0);
    }
  };

  issue_loads(0, 0);
  write_stage(0, wsc[sbase]);

  for (int ktl = 0; ktl < nkt; ++ktl) {
    const int cur = ktl & 1;
    __syncthreads();                                   // buf[cur] ready
    if (ktl + 1 < nkt) issue_loads(ktl + 1, cur ^ 1);  // async, early
    compute(cur);                                      // hides latency
    if (ktl + 1 < nkt) write_stage(cur ^ 1, wsc[sbase + ((ktl + 1) >> 1)]);
  }

  float* dst = outp + (SPLIT ? (size_t)kh * MDIM * NDIM : 0);
#pragma unroll
  for (int i = 0; i < 4; ++i) {
#pragma unroll
    for (int j = 0; j < 4; ++j) {
      const int mrow = m0 + wm + i * 16 + (l >> 4) * 4;
      const int ocol = n0 + wn + j * 16 + (l & 15);
#pragma unroll
      for (int r = 0; r < 4; ++r)
        dst[(size_t)(mrow + r) * NDIM + ocol] = acc[i][j][r];
    }
  }
}

extern "C" void kernel_launch(void* const* d_in, const int* in_sizes, int n_in,
                              void* d_out, int out_size, void* d_ws,
                              size_t ws_size, hipStream_t stream) {
  const float* x = (const float*)d_in[0];
  const int* wq = (const int*)d_in[1];
  const float* wsc = (const float*)d_in[2];
  float* out = (float*)d_out;

  const size_t xb_bytes = (size_t)MDIM * KDIM * sizeof(short);          // 8 MB
  const size_t part_bytes = (size_t)2 * MDIM * NDIM * sizeof(float);    // 32 MB

  if (ws_size >= xb_bytes + part_bytes) {
    short* xb = (short*)d_ws;
    float* part = (float*)((char*)d_ws + xb_bytes);
    cvt_x_kernel<<<dim3(2048), dim3(256), 0, stream>>>(x, xb);
    gemm_q_kernel<true, true><<<dim3(512), dim3(256), 0, stream>>>(
        xb, x, wq, wsc, part);
    reduce_kernel<<<dim3(4096), dim3(256), 0, stream>>>(part, out);
  } else if (ws_size >= xb_bytes) {
    short* xb = (short*)d_ws;
    cvt_x_kernel<<<dim3(2048), dim3(256), 0, stream>>>(x, xb);
    gemm_q_kernel<false, true><<<dim3(256), dim3(256), 0, stream>>>(
        xb, x, wq, wsc, out);
  } else {
    gemm_q_kernel<false, false><<<dim3(256), dim3(256), 0, stream>>>(
        nullptr, x, wq, wsc, out);
  }
}